// Round 1
// baseline (315.163 us; speedup 1.0000x reference)
//
#include <hip/hip_runtime.h>

// GraphAttentionLayer: x(8192,512) f32, support(8192,8192) i32{0,1},
// W(512,256) f32, a(512,1) f32  ->  out(8192,256) f32
//
// Decomposition (softmax shift cancels in numerator/denominator):
//   h = x@W (bf16 MFMA)
//   s = h@a1, t = h@a2, u = s+t
//   top rows i<4096 : out = elu((eL*TL + eR*TR)/(eL*TL[256] + eR*TR[256]))
//       TL = sup[0:4096, 0:4096]   @ [h|1],  TR = sup[0:4096, 4096:] @ [h|1]
//       eL = exp(leaky(u[2i])), eR = exp(leaky(u[2i+1]))
//   bot rows i>=4096: out = elu(TB/TB[256]),  TB = sup[4096:, :] @ (wb .* [h|1])
//       wb[j] = exp(leaky(s[2j%N] + t[(2j+1)%N]))

typedef short bf16x8 __attribute__((ext_vector_type(8)));
typedef float f32x4 __attribute__((ext_vector_type(4)));

static __device__ __forceinline__ unsigned short f2bf(float f) {
    unsigned int u = __builtin_bit_cast(unsigned int, f);
    unsigned int r = (u + 0x7FFFu + ((u >> 16) & 1u)) >> 16;
    return (unsigned short)r;
}
static __device__ __forceinline__ float bf2f(unsigned short s) {
    unsigned int u = ((unsigned int)s) << 16;
    return __builtin_bit_cast(float, u);
}

// ---- k1a: x f32 -> bf16 row-major [8192][512]
__global__ __launch_bounds__(256) void k_cvt_x(const float* __restrict__ x,
                                               unsigned short* __restrict__ xb) {
    int i = (blockIdx.x * 256 + threadIdx.x) * 4;
    float4 v = *(const float4*)(x + i);
    ushort4 o = make_ushort4(f2bf(v.x), f2bf(v.y), f2bf(v.z), f2bf(v.w));
    *(ushort4*)(xb + i) = o;
}

// ---- k1b: W [512][256] f32 -> Wbt [256][512] bf16 (n-major, k-contiguous)
__global__ __launch_bounds__(256) void k_cvt_w(const float* __restrict__ W,
                                               unsigned short* __restrict__ Wbt) {
    int idx = blockIdx.x * 256 + threadIdx.x;   // 131072 total
    int n = idx >> 9, k = idx & 511;
    Wbt[idx] = f2bf(W[k * 256 + n]);
}

// ---- k2: h = xb @ Wbt^T.  Writes h row-major bf16 [8192][256] AND
//          B1t transposed [272][8192] rows 0..255 (MFMA B-operand layout).
__global__ __launch_bounds__(256) void k_gemm_h(const unsigned short* __restrict__ xb,
                                                const unsigned short* __restrict__ Wbt,
                                                unsigned short* __restrict__ h,
                                                unsigned short* __restrict__ B1t) {
    __shared__ unsigned short Asm[128][72];   // +8 pad: keeps 16B align, spreads banks
    __shared__ unsigned short Bsm[64][72];
    int tid = threadIdx.x;
    int wv = tid >> 6, ln = tid & 63;
    int m0 = blockIdx.x * 128, n0 = blockIdx.y * 64;

    f32x4 acc[2][4];
#pragma unroll
    for (int i = 0; i < 2; i++)
#pragma unroll
        for (int j = 0; j < 4; j++) acc[i][j] = (f32x4)0.0f;

    for (int k0 = 0; k0 < 512; k0 += 64) {
        {   // stage A 128x64
            int r = tid >> 1, c = (tid & 1) * 32;
            const unsigned short* src = xb + (m0 + r) * 512 + k0 + c;
            *(bf16x8*)&Asm[r][c]      = *(const bf16x8*)(src);
            *(bf16x8*)&Asm[r][c + 8]  = *(const bf16x8*)(src + 8);
            *(bf16x8*)&Asm[r][c + 16] = *(const bf16x8*)(src + 16);
            *(bf16x8*)&Asm[r][c + 24] = *(const bf16x8*)(src + 24);
        }
        {   // stage B 64x64
            int r = tid >> 2, c = (tid & 3) * 16;
            const unsigned short* src = Wbt + (n0 + r) * 512 + k0 + c;
            *(bf16x8*)&Bsm[r][c]     = *(const bf16x8*)(src);
            *(bf16x8*)&Bsm[r][c + 8] = *(const bf16x8*)(src + 8);
        }
        __syncthreads();
        int lr = ln & 15, lk = (ln >> 4) * 8;
#pragma unroll
        for (int ks = 0; ks < 2; ks++) {
            int kk = ks * 32 + lk;
            bf16x8 a0 = *(const bf16x8*)&Asm[wv * 32 + lr][kk];
            bf16x8 a1 = *(const bf16x8*)&Asm[wv * 32 + 16 + lr][kk];
#pragma unroll
            for (int nt = 0; nt < 4; nt++) {
                bf16x8 b = *(const bf16x8*)&Bsm[nt * 16 + lr][kk];
                acc[0][nt] = __builtin_amdgcn_mfma_f32_16x16x32_bf16(a0, b, acc[0][nt], 0, 0, 0);
                acc[1][nt] = __builtin_amdgcn_mfma_f32_16x16x32_bf16(a1, b, acc[1][nt], 0, 0, 0);
            }
        }
        __syncthreads();
    }
    // epilogue: C layout col=lane&15, row=(lane>>4)*4+reg  [m89-verified]
    int lr = ln & 15, lrow = (ln >> 4) * 4;
#pragma unroll
    for (int mt = 0; mt < 2; mt++) {
#pragma unroll
        for (int nt = 0; nt < 4; nt++) {
            int mg = m0 + wv * 32 + mt * 16 + lrow;
            int ng = n0 + nt * 16 + lr;
            ushort4 tb = make_ushort4(f2bf(acc[mt][nt][0]), f2bf(acc[mt][nt][1]),
                                      f2bf(acc[mt][nt][2]), f2bf(acc[mt][nt][3]));
            h[(mg + 0) * 256 + ng] = tb.x;
            h[(mg + 1) * 256 + ng] = tb.y;
            h[(mg + 2) * 256 + ng] = tb.z;
            h[(mg + 3) * 256 + ng] = tb.w;
            *(ushort4*)&B1t[ng * 8192 + mg] = tb;   // transposed copy
        }
    }
}

// ---- k3: s[j] = h[j,:]@a1, t[j] = h[j,:]@a2 (one wave per row)
__global__ __launch_bounds__(256) void k_st(const unsigned short* __restrict__ h,
                                            const float* __restrict__ a,
                                            float* __restrict__ s, float* __restrict__ t) {
    int wv = threadIdx.x >> 6, ln = threadIdx.x & 63;
    int j = blockIdx.x * 4 + wv;
    ushort4 hv = *(const ushort4*)(h + j * 256 + ln * 4);
    float4 a1 = *(const float4*)(a + ln * 4);
    float4 a2 = *(const float4*)(a + 256 + ln * 4);
    float s_ = bf2f(hv.x) * a1.x + bf2f(hv.y) * a1.y + bf2f(hv.z) * a1.z + bf2f(hv.w) * a1.w;
    float t_ = bf2f(hv.x) * a2.x + bf2f(hv.y) * a2.y + bf2f(hv.z) * a2.z + bf2f(hv.w) * a2.w;
#pragma unroll
    for (int off = 32; off; off >>= 1) {
        s_ += __shfl_down(s_, off);
        t_ += __shfl_down(t_, off);
    }
    if (ln == 0) { s[j] = s_; t[j] = t_; }
}

// ---- k3b: wb / eL / eR; fill B1t aux rows (256 = ones, 257..271 = 0)
__global__ __launch_bounds__(256) void k_weights(const float* __restrict__ s,
                                                 const float* __restrict__ t,
                                                 float* __restrict__ wb,
                                                 float* __restrict__ eL,
                                                 float* __restrict__ eR,
                                                 unsigned short* __restrict__ B1t) {
    int j = blockIdx.x * 256 + threadIdx.x;   // 0..8191
    float eb = s[(2 * j) & 8191] + t[(2 * j + 1) & 8191];
    eb = eb > 0.0f ? eb : 0.2f * eb;
    wb[j] = expf(eb);
    if (j < 4096) {
        float cL = s[2 * j] + t[2 * j];
        cL = cL > 0.0f ? cL : 0.2f * cL;
        float cR = s[2 * j + 1] + t[2 * j + 1];
        cR = cR > 0.0f ? cR : 0.2f * cR;
        eL[j] = expf(cL);
        eR[j] = expf(cR);
    }
    B1t[256 * 8192 + j] = 0x3F80;   // 1.0bf16
#pragma unroll
    for (int f = 257; f < 272; f++) B1t[f * 8192 + j] = 0;
}

// ---- k4: B2t[f][j] = wb[j] * B1t[f][j]
__global__ __launch_bounds__(256) void k_b2(const unsigned short* __restrict__ B1t,
                                            const float* __restrict__ wb,
                                            unsigned short* __restrict__ B2t) {
    int j = blockIdx.x * 256 + threadIdx.x;
    int f = blockIdx.y;
    B2t[f * 8192 + j] = f2bf(wb[j] * bf2f(B1t[f * 8192 + j]));
}

// ---- k5: masked GEMM  out[seg] = sup[M0:M0+4096, K0:K0+4096] @ Bt  (272 cols)
// seg 0: TL (B1t), 1: TR (B1t), 2: TB0 (B2t), 3: TB1 (B2t)
__global__ __launch_bounds__(256) void k_mgemm(const int* __restrict__ sup,
                                               const unsigned short* __restrict__ B1t,
                                               const unsigned short* __restrict__ B2t,
                                               float* __restrict__ TL, float* __restrict__ TR,
                                               float* __restrict__ TB0, float* __restrict__ TB1) {
    __shared__ unsigned short Asm[64][72];
    __shared__ unsigned short Bsm[272][72];
    int seg = blockIdx.y;
    int M0 = (seg >= 2) ? 4096 : 0;
    int K0 = (seg & 1) ? 4096 : 0;
    const unsigned short* Bt = (seg >= 2) ? B2t : B1t;
    float* out = (seg == 0) ? TL : (seg == 1) ? TR : (seg == 2) ? TB0 : TB1;

    int tid = threadIdx.x;
    int wv = tid >> 6, ln = tid & 63;
    long m0 = M0 + blockIdx.x * 64;

    f32x4 acc[17];
#pragma unroll
    for (int i = 0; i < 17; i++) acc[i] = (f32x4)0.0f;

    for (int kb = 0; kb < 4096; kb += 64) {
        {   // stage A: 64 rows x 64 int32 -> bf16 {0,1}
            int r = tid >> 2, c = (tid & 3) * 16;
            const int* src = sup + (m0 + r) * 8192 + K0 + kb + c;
            int4 v0 = *(const int4*)(src);
            int4 v1 = *(const int4*)(src + 4);
            int4 v2 = *(const int4*)(src + 8);
            int4 v3 = *(const int4*)(src + 12);
            *(ushort4*)&Asm[r][c]      = make_ushort4(v0.x ? 0x3F80 : 0, v0.y ? 0x3F80 : 0,
                                                      v0.z ? 0x3F80 : 0, v0.w ? 0x3F80 : 0);
            *(ushort4*)&Asm[r][c + 4]  = make_ushort4(v1.x ? 0x3F80 : 0, v1.y ? 0x3F80 : 0,
                                                      v1.z ? 0x3F80 : 0, v1.w ? 0x3F80 : 0);
            *(ushort4*)&Asm[r][c + 8]  = make_ushort4(v2.x ? 0x3F80 : 0, v2.y ? 0x3F80 : 0,
                                                      v2.z ? 0x3F80 : 0, v2.w ? 0x3F80 : 0);
            *(ushort4*)&Asm[r][c + 12] = make_ushort4(v3.x ? 0x3F80 : 0, v3.y ? 0x3F80 : 0,
                                                      v3.z ? 0x3F80 : 0, v3.w ? 0x3F80 : 0);
        }
        // stage B: 272 rows x 64 bf16
        for (int idx = tid; idx < 272 * 8; idx += 256) {
            int r = idx >> 3, c = (idx & 7) * 8;
            *(bf16x8*)&Bsm[r][c] = *(const bf16x8*)(Bt + (long)r * 8192 + K0 + kb + c);
        }
        __syncthreads();
        int lr = ln & 15, lk = (ln >> 4) * 8;
#pragma unroll
        for (int ks = 0; ks < 2; ks++) {
            int kk = ks * 32 + lk;
            bf16x8 av = *(const bf16x8*)&Asm[wv * 16 + lr][kk];
#pragma unroll
            for (int nt = 0; nt < 17; nt++) {
                bf16x8 bv = *(const bf16x8*)&Bsm[nt * 16 + lr][kk];
                acc[nt] = __builtin_amdgcn_mfma_f32_16x16x32_bf16(av, bv, acc[nt], 0, 0, 0);
            }
        }
        __syncthreads();
    }
    int lr = ln & 15, lrow = (ln >> 4) * 4;
    long mrow = blockIdx.x * 64 + wv * 16 + lrow;
#pragma unroll
    for (int nt = 0; nt < 17; nt++) {
#pragma unroll
        for (int r = 0; r < 4; r++) out[(mrow + r) * 272 + nt * 16 + lr] = acc[nt][r];
    }
}

// ---- k6: combine + elu
__global__ __launch_bounds__(256) void k_out(const float* __restrict__ TL,
                                             const float* __restrict__ TR,
                                             const float* __restrict__ TB0,
                                             const float* __restrict__ TB1,
                                             const float* __restrict__ eL,
                                             const float* __restrict__ eR,
                                             float* __restrict__ outp) {
    int i = blockIdx.x, f = threadIdx.x;
    float num, den;
    if (i < 4096) {
        float el = eL[i], er = eR[i];
        den = el * TL[i * 272 + 256] + er * TR[i * 272 + 256];
        num = el * TL[i * 272 + f] + er * TR[i * 272 + f];
    } else {
        int ii = i - 4096;
        den = TB0[ii * 272 + 256] + TB1[ii * 272 + 256];
        num = TB0[ii * 272 + f] + TB1[ii * 272 + f];
    }
    float r = num / den;
    outp[i * 256 + f] = r > 0.0f ? r : expm1f(r);
}

extern "C" void kernel_launch(void* const* d_in, const int* in_sizes, int n_in,
                              void* d_out, int out_size, void* d_ws, size_t ws_size,
                              hipStream_t stream) {
    (void)in_sizes; (void)n_in; (void)out_size; (void)ws_size;
    const float* x = (const float*)d_in[0];
    const int* sup = (const int*)d_in[1];
    const float* W = (const float*)d_in[2];
    const float* a = (const float*)d_in[3];
    float* outp = (float*)d_out;

    char* ws = (char*)d_ws;
    size_t off = 0;
    auto alloc = [&](size_t bytes) -> void* {
        void* p = ws + off;
        off += (bytes + 255) & ~(size_t)255;
        return p;
    };
    unsigned short* xb  = (unsigned short*)alloc(8192 * 512 * 2);
    unsigned short* Wbt = (unsigned short*)alloc(256 * 512 * 2);
    unsigned short* h   = (unsigned short*)alloc(8192 * 256 * 2);
    unsigned short* B1t = (unsigned short*)alloc(272 * 8192 * 2);
    unsigned short* B2t = (unsigned short*)alloc(272 * 8192 * 2);
    float* s   = (float*)alloc(8192 * 4);
    float* t   = (float*)alloc(8192 * 4);
    float* wb  = (float*)alloc(8192 * 4);
    float* eL  = (float*)alloc(4096 * 4);
    float* eR  = (float*)alloc(4096 * 4);
    float* TL  = (float*)alloc(4096 * 272 * 4);
    float* TR  = (float*)alloc(4096 * 272 * 4);
    float* TB0 = (float*)alloc(4096 * 272 * 4);
    float* TB1 = (float*)alloc(4096 * 272 * 4);

    k_cvt_x<<<4096, 256, 0, stream>>>(x, xb);
    k_cvt_w<<<512, 256, 0, stream>>>(W, Wbt);
    k_gemm_h<<<dim3(64, 4), 256, 0, stream>>>(xb, Wbt, h, B1t);
    k_st<<<2048, 256, 0, stream>>>(h, a, s, t);
    k_weights<<<32, 256, 0, stream>>>(s, t, wb, eL, eR, B1t);
    k_b2<<<dim3(32, 272), 256, 0, stream>>>(B1t, wb, B2t);
    k_mgemm<<<dim3(64, 4), 256, 0, stream>>>(sup, B1t, B2t, TL, TR, TB0, TB1);
    k_out<<<8192, 256, 0, stream>>>(TL, TR, TB0, TB1, eL, eR, outp);
}

// Round 2
// 192.903 us; speedup vs baseline: 1.6338x; 1.6338x over previous
//
#include <hip/hip_runtime.h>

// GraphAttentionLayer: x(8192,512) f32, support(8192,8192) i32{0,1},
// W(512,256) f32, a(512,1) f32  ->  out(8192,256) f32
//
// Decomposition (softmax shift cancels in numerator/denominator):
//   h = x@W (bf16 MFMA)
//   s = h@a1, t = h@a2, u = s+t
//   top rows i<4096 : out = elu((eL*TL + eR*TR)/(eL*TL[256] + eR*TR[256]))
//   bot rows i>=4096: out = elu(TB/TB[256]),  TB = sup[4096:, :] @ (wb .* [h|1])

typedef short bf16x8 __attribute__((ext_vector_type(8)));
typedef float f32x4 __attribute__((ext_vector_type(4)));

static __device__ __forceinline__ unsigned short f2bf(float f) {
    unsigned int u = __builtin_bit_cast(unsigned int, f);
    unsigned int r = (u + 0x7FFFu + ((u >> 16) & 1u)) >> 16;
    return (unsigned short)r;
}
static __device__ __forceinline__ float bf2f(unsigned short s) {
    unsigned int u = ((unsigned int)s) << 16;
    return __builtin_bit_cast(float, u);
}

// ---- k1a: x f32 -> bf16 row-major [8192][512]
__global__ __launch_bounds__(256) void k_cvt_x(const float* __restrict__ x,
                                               unsigned short* __restrict__ xb) {
    int i = (blockIdx.x * 256 + threadIdx.x) * 4;
    float4 v = *(const float4*)(x + i);
    ushort4 o = make_ushort4(f2bf(v.x), f2bf(v.y), f2bf(v.z), f2bf(v.w));
    *(ushort4*)(xb + i) = o;
}

// ---- k1b: W [512][256] f32 -> Wbt [256][512] bf16 (n-major, k-contiguous)
__global__ __launch_bounds__(256) void k_cvt_w(const float* __restrict__ W,
                                               unsigned short* __restrict__ Wbt) {
    int idx = blockIdx.x * 256 + threadIdx.x;
    int n = idx >> 9, k = idx & 511;
    Wbt[idx] = f2bf(W[k * 256 + n]);
}

// ---- k2: h = xb @ Wbt^T. Writes h row-major bf16 AND B1t [272][8192] rows 0..255.
__global__ __launch_bounds__(256) void k_gemm_h(const unsigned short* __restrict__ xb,
                                                const unsigned short* __restrict__ Wbt,
                                                unsigned short* __restrict__ h,
                                                unsigned short* __restrict__ B1t) {
    __shared__ unsigned short Asm[128][72];
    __shared__ unsigned short Bsm[64][72];
    int tid = threadIdx.x;
    int wv = tid >> 6, ln = tid & 63;
    int m0 = blockIdx.x * 128, n0 = blockIdx.y * 64;

    f32x4 acc[2][4];
#pragma unroll
    for (int i = 0; i < 2; i++)
#pragma unroll
        for (int j = 0; j < 4; j++) acc[i][j] = (f32x4)0.0f;

    for (int k0 = 0; k0 < 512; k0 += 64) {
        {
            int r = tid >> 1, c = (tid & 1) * 32;
            const unsigned short* src = xb + (m0 + r) * 512 + k0 + c;
            *(bf16x8*)&Asm[r][c]      = *(const bf16x8*)(src);
            *(bf16x8*)&Asm[r][c + 8]  = *(const bf16x8*)(src + 8);
            *(bf16x8*)&Asm[r][c + 16] = *(const bf16x8*)(src + 16);
            *(bf16x8*)&Asm[r][c + 24] = *(const bf16x8*)(src + 24);
        }
        {
            int r = tid >> 2, c = (tid & 3) * 16;
            const unsigned short* src = Wbt + (n0 + r) * 512 + k0 + c;
            *(bf16x8*)&Bsm[r][c]     = *(const bf16x8*)(src);
            *(bf16x8*)&Bsm[r][c + 8] = *(const bf16x8*)(src + 8);
        }
        __syncthreads();
        int lr = ln & 15, lk = (ln >> 4) * 8;
#pragma unroll
        for (int ks = 0; ks < 2; ks++) {
            int kk = ks * 32 + lk;
            bf16x8 a0 = *(const bf16x8*)&Asm[wv * 32 + lr][kk];
            bf16x8 a1 = *(const bf16x8*)&Asm[wv * 32 + 16 + lr][kk];
#pragma unroll
            for (int nt = 0; nt < 4; nt++) {
                bf16x8 b = *(const bf16x8*)&Bsm[nt * 16 + lr][kk];
                acc[0][nt] = __builtin_amdgcn_mfma_f32_16x16x32_bf16(a0, b, acc[0][nt], 0, 0, 0);
                acc[1][nt] = __builtin_amdgcn_mfma_f32_16x16x32_bf16(a1, b, acc[1][nt], 0, 0, 0);
            }
        }
        __syncthreads();
    }
    int lr = ln & 15, lrow = (ln >> 4) * 4;
#pragma unroll
    for (int mt = 0; mt < 2; mt++) {
#pragma unroll
        for (int nt = 0; nt < 4; nt++) {
            int mg = m0 + wv * 32 + mt * 16 + lrow;
            int ng = n0 + nt * 16 + lr;
            ushort4 tb = make_ushort4(f2bf(acc[mt][nt][0]), f2bf(acc[mt][nt][1]),
                                      f2bf(acc[mt][nt][2]), f2bf(acc[mt][nt][3]));
            h[(mg + 0) * 256 + ng] = tb.x;
            h[(mg + 1) * 256 + ng] = tb.y;
            h[(mg + 2) * 256 + ng] = tb.z;
            h[(mg + 3) * 256 + ng] = tb.w;
            *(ushort4*)&B1t[ng * 8192 + mg] = tb;
        }
    }
}

// ---- k3: s[j], t[j]
__global__ __launch_bounds__(256) void k_st(const unsigned short* __restrict__ h,
                                            const float* __restrict__ a,
                                            float* __restrict__ s, float* __restrict__ t) {
    int wv = threadIdx.x >> 6, ln = threadIdx.x & 63;
    int j = blockIdx.x * 4 + wv;
    ushort4 hv = *(const ushort4*)(h + j * 256 + ln * 4);
    float4 a1 = *(const float4*)(a + ln * 4);
    float4 a2 = *(const float4*)(a + 256 + ln * 4);
    float s_ = bf2f(hv.x) * a1.x + bf2f(hv.y) * a1.y + bf2f(hv.z) * a1.z + bf2f(hv.w) * a1.w;
    float t_ = bf2f(hv.x) * a2.x + bf2f(hv.y) * a2.y + bf2f(hv.z) * a2.z + bf2f(hv.w) * a2.w;
#pragma unroll
    for (int off = 32; off; off >>= 1) {
        s_ += __shfl_down(s_, off);
        t_ += __shfl_down(t_, off);
    }
    if (ln == 0) { s[j] = s_; t[j] = t_; }
}

// ---- k3b: wb / eL / eR; fill B1t aux rows
__global__ __launch_bounds__(256) void k_weights(const float* __restrict__ s,
                                                 const float* __restrict__ t,
                                                 float* __restrict__ wb,
                                                 float* __restrict__ eL,
                                                 float* __restrict__ eR,
                                                 unsigned short* __restrict__ B1t) {
    int j = blockIdx.x * 256 + threadIdx.x;
    float eb = s[(2 * j) & 8191] + t[(2 * j + 1) & 8191];
    eb = eb > 0.0f ? eb : 0.2f * eb;
    wb[j] = expf(eb);
    if (j < 4096) {
        float cL = s[2 * j] + t[2 * j];
        cL = cL > 0.0f ? cL : 0.2f * cL;
        float cR = s[2 * j + 1] + t[2 * j + 1];
        cR = cR > 0.0f ? cR : 0.2f * cR;
        eL[j] = expf(cL);
        eR[j] = expf(cR);
    }
    B1t[256 * 8192 + j] = 0x3F80;
#pragma unroll
    for (int f = 257; f < 272; f++) B1t[f * 8192 + j] = 0;
}

// ---- k4: B2t[f][j] = wb[j] * B1t[f][j]
__global__ __launch_bounds__(256) void k_b2(const unsigned short* __restrict__ B1t,
                                            const float* __restrict__ wb,
                                            unsigned short* __restrict__ B2t) {
    int j = blockIdx.x * 256 + threadIdx.x;
    int f = blockIdx.y;
    B2t[f * 8192 + j] = f2bf(wb[j] * bf2f(B1t[f * 8192 + j]));
}

// ---- k5: masked GEMM, 2-deep pipelined, K-split x2, atomic accumulate.
// grid (64 mblk, 4 seg, 2 khalf); BM=64, BN=272, BK=32, dbuf LDS, 1 barrier/iter.
__global__ __launch_bounds__(256) void k_mgemm(const int* __restrict__ sup,
                                               const unsigned short* __restrict__ B1t,
                                               const unsigned short* __restrict__ B2t,
                                               float* __restrict__ TL, float* __restrict__ TR,
                                               float* __restrict__ TB0, float* __restrict__ TB1) {
    __shared__ unsigned short Asm[2][64][40];   // pad 32->40: 2-way max conflict
    __shared__ unsigned short Bsm[2][272][40];
    int seg = blockIdx.y, kh = blockIdx.z;
    long M0 = (seg >= 2) ? 4096 : 0;
    long K0 = ((seg & 1) ? 4096 : 0) + (long)kh * 2048;
    const unsigned short* Bt = (seg >= 2) ? B2t : B1t;
    float* out = (seg == 0) ? TL : (seg == 1) ? TR : (seg == 2) ? TB0 : TB1;

    int tid = threadIdx.x;
    int wv = tid >> 6, ln = tid & 63;
    long m0 = M0 + blockIdx.x * 64;

    // A: thread covers row tid>>2, 8 ints at col (tid&3)*8 (2x int4, 32B contiguous)
    const int* asrc = sup + (m0 + (tid >> 2)) * 8192 + K0 + (tid & 3) * 8;
    int arow = tid >> 2, acol = (tid & 3) * 8;

    f32x4 acc[17];
#pragma unroll
    for (int i = 0; i < 17; i++) acc[i] = (f32x4)0.0f;

    int4 ra0, ra1;
    bf16x8 rb[5];

    // ---- prologue: load tile 0 into regs
    ra0 = *(const int4*)(asrc);
    ra1 = *(const int4*)(asrc + 4);
#pragma unroll
    for (int i = 0; i < 4; i++) {
        int c = tid + 256 * i;                   // chunk: row c>>2, 8 bf16 at (c&3)*8
        rb[i] = *(const bf16x8*)(Bt + (long)(c >> 2) * 8192 + K0 + (c & 3) * 8);
    }
    if (tid < 64) {
        int c = 1024 + tid;
        rb[4] = *(const bf16x8*)(Bt + (long)(c >> 2) * 8192 + K0 + (c & 3) * 8);
    }
    {   // convert + write buf 0
        bf16x8 aw;
        aw[0] = ra0.x ? 0x3F80 : 0; aw[1] = ra0.y ? 0x3F80 : 0;
        aw[2] = ra0.z ? 0x3F80 : 0; aw[3] = ra0.w ? 0x3F80 : 0;
        aw[4] = ra1.x ? 0x3F80 : 0; aw[5] = ra1.y ? 0x3F80 : 0;
        aw[6] = ra1.z ? 0x3F80 : 0; aw[7] = ra1.w ? 0x3F80 : 0;
        *(bf16x8*)&Asm[0][arow][acol] = aw;
#pragma unroll
        for (int i = 0; i < 4; i++) {
            int c = tid + 256 * i;
            *(bf16x8*)&Bsm[0][c >> 2][(c & 3) * 8] = rb[i];
        }
        if (tid < 64) {
            int c = 1024 + tid;
            *(bf16x8*)&Bsm[0][c >> 2][(c & 3) * 8] = rb[4];
        }
    }

    int lr = ln & 15, lk = (ln >> 4) * 8;
#pragma unroll 2
    for (int k = 0; k < 64; k++) {
        __syncthreads();
        int cur = k & 1;
        if (k + 1 < 64) {   // prefetch tile k+1 into regs (T14: issue early)
            const int* a2 = asrc + (k + 1) * 32;
            ra0 = *(const int4*)(a2);
            ra1 = *(const int4*)(a2 + 4);
#pragma unroll
            for (int i = 0; i < 4; i++) {
                int c = tid + 256 * i;
                rb[i] = *(const bf16x8*)(Bt + (long)(c >> 2) * 8192 + K0 + (k + 1) * 32 + (c & 3) * 8);
            }
            if (tid < 64) {
                int c = 1024 + tid;
                rb[4] = *(const bf16x8*)(Bt + (long)(c >> 2) * 8192 + K0 + (k + 1) * 32 + (c & 3) * 8);
            }
        }
        // compute on buf cur
        bf16x8 av = *(const bf16x8*)&Asm[cur][wv * 16 + lr][lk];
#pragma unroll
        for (int nt = 0; nt < 17; nt++) {
            bf16x8 bv = *(const bf16x8*)&Bsm[cur][nt * 16 + lr][lk];
            acc[nt] = __builtin_amdgcn_mfma_f32_16x16x32_bf16(av, bv, acc[nt], 0, 0, 0);
        }
        if (k + 1 < 64) {   // write tile k+1 to other buffer (compiler waits vmcnt)
            bf16x8 aw;
            aw[0] = ra0.x ? 0x3F80 : 0; aw[1] = ra0.y ? 0x3F80 : 0;
            aw[2] = ra0.z ? 0x3F80 : 0; aw[3] = ra0.w ? 0x3F80 : 0;
            aw[4] = ra1.x ? 0x3F80 : 0; aw[5] = ra1.y ? 0x3F80 : 0;
            aw[6] = ra1.z ? 0x3F80 : 0; aw[7] = ra1.w ? 0x3F80 : 0;
            *(bf16x8*)&Asm[cur ^ 1][arow][acol] = aw;
#pragma unroll
            for (int i = 0; i < 4; i++) {
                int c = tid + 256 * i;
                *(bf16x8*)&Bsm[cur ^ 1][c >> 2][(c & 3) * 8] = rb[i];
            }
            if (tid < 64) {
                int c = 1024 + tid;
                *(bf16x8*)&Bsm[cur ^ 1][c >> 2][(c & 3) * 8] = rb[4];
            }
        }
    }
    // epilogue: atomic accumulate (2 contributors per element -> deterministic)
    int lrow = (ln >> 4) * 4;
    long mrow = blockIdx.x * 64 + wv * 16 + lrow;
#pragma unroll
    for (int nt = 0; nt < 17; nt++) {
#pragma unroll
        for (int r = 0; r < 4; r++)
            unsafeAtomicAdd(&out[(mrow + r) * 272 + nt * 16 + lr], acc[nt][r]);
    }
}

// ---- k6: combine + elu
__global__ __launch_bounds__(256) void k_out(const float* __restrict__ TL,
                                             const float* __restrict__ TR,
                                             const float* __restrict__ TB0,
                                             const float* __restrict__ TB1,
                                             const float* __restrict__ eL,
                                             const float* __restrict__ eR,
                                             float* __restrict__ outp) {
    int i = blockIdx.x, f = threadIdx.x;
    float num, den;
    if (i < 4096) {
        float el = eL[i], er = eR[i];
        den = el * TL[i * 272 + 256] + er * TR[i * 272 + 256];
        num = el * TL[i * 272 + f] + er * TR[i * 272 + f];
    } else {
        int ii = i - 4096;
        den = TB0[ii * 272 + 256] + TB1[ii * 272 + 256];
        num = TB0[ii * 272 + f] + TB1[ii * 272 + f];
    }
    float r = num / den;
    outp[i * 256 + f] = r > 0.0f ? r : expm1f(r);
}

extern "C" void kernel_launch(void* const* d_in, const int* in_sizes, int n_in,
                              void* d_out, int out_size, void* d_ws, size_t ws_size,
                              hipStream_t stream) {
    (void)in_sizes; (void)n_in; (void)out_size; (void)ws_size;
    const float* x = (const float*)d_in[0];
    const int* sup = (const int*)d_in[1];
    const float* W = (const float*)d_in[2];
    const float* a = (const float*)d_in[3];
    float* outp = (float*)d_out;

    char* ws = (char*)d_ws;
    size_t off = 0;
    auto alloc = [&](size_t bytes) -> void* {
        void* p = ws + off;
        off += (bytes + 255) & ~(size_t)255;
        return p;
    };
    unsigned short* xb  = (unsigned short*)alloc(8192 * 512 * 2);
    unsigned short* Wbt = (unsigned short*)alloc(256 * 512 * 2);
    unsigned short* h   = (unsigned short*)alloc(8192 * 256 * 2);
    unsigned short* B1t = (unsigned short*)alloc(272 * 8192 * 2);
    unsigned short* B2t = (unsigned short*)alloc(272 * 8192 * 2);
    float* s   = (float*)alloc(8192 * 4);
    float* t   = (float*)alloc(8192 * 4);
    float* wb  = (float*)alloc(8192 * 4);
    float* eL  = (float*)alloc(4096 * 4);
    float* eR  = (float*)alloc(4096 * 4);
    float* TL  = (float*)alloc(4096 * 272 * 4);
    float* TR  = (float*)alloc(4096 * 272 * 4);
    float* TB0 = (float*)alloc(4096 * 272 * 4);
    float* TB1 = (float*)alloc(4096 * 272 * 4);

    // zero accumulators (k_mgemm atomically adds into them)
    hipMemsetAsync(TL, 0, (size_t)4 * 4096 * 272 * 4 + 3 * 256, stream); // TL..TB1 contiguous (256B-aligned)

    k_cvt_x<<<4096, 256, 0, stream>>>(x, xb);
    k_cvt_w<<<512, 256, 0, stream>>>(W, Wbt);
    k_gemm_h<<<dim3(64, 4), 256, 0, stream>>>(xb, Wbt, h, B1t);
    k_st<<<2048, 256, 0, stream>>>(h, a, s, t);
    k_weights<<<32, 256, 0, stream>>>(s, t, wb, eL, eR, B1t);
    k_b2<<<dim3(32, 272), 256, 0, stream>>>(B1t, wb, B2t);
    k_mgemm<<<dim3(64, 4, 2), 256, 0, stream>>>(sup, B1t, B2t, TL, TR, TB0, TB1);
    k_out<<<8192, 256, 0, stream>>>(TL, TR, TB0, TB1, eL, eR, outp);
}